// Round 3
// baseline (362.634 us; speedup 1.0000x reference)
//
#include <hip/hip_runtime.h>
#include <hip/hip_bf16.h>
#include <math.h>

#define B_  4
#define T_  2048
#define C_  1024
#define NH_ 16
#define HD_ 64

using bf16 = __hip_bfloat16;
typedef __attribute__((ext_vector_type(8))) short bf16x8;   // 8 bf16 (4 VGPRs)
typedef __attribute__((ext_vector_type(4))) short bf16x4;   // 4 bf16 (2 VGPRs)
typedef __attribute__((ext_vector_type(4))) float f32x4;

__device__ __forceinline__ bf16 f2b(float f){ return __float2bfloat16(f); }
__device__ __forceinline__ short f2bs(float f){ bf16 b = __float2bfloat16(f); return *(short*)&b; }

__device__ __forceinline__ void async_load16(const bf16* g, bf16* l){
  __builtin_amdgcn_global_load_lds((const __attribute__((address_space(1))) unsigned int*)g,
                                   (__attribute__((address_space(3))) unsigned int*)l,
                                   16, 0, 0);
}

// 0.125 (1/sqrt(64)) * log2(e): softmax runs in exp2 domain
#define QSCALE 0.18033688011112042f

// ---------------- conversion kernels ----------------

__global__ __launch_bounds__(256) void k_cvt4(const float* __restrict__ in, bf16* __restrict__ out, int n){
  int i = (blockIdx.x * 256 + threadIdx.x) * 4;
  if (i < n){
    float4 f = *(const float4*)(in + i);
    ushort4 u;
    u.x = (unsigned short)f2bs(f.x);
    u.y = (unsigned short)f2bs(f.y);
    u.z = (unsigned short)f2bs(f.z);
    u.w = (unsigned short)f2bs(f.w);
    *(ushort4*)(out + i) = u;
  }
}

// in [R][Cc] fp32 -> out [Cc][R] bf16, LDS tile transpose
__global__ __launch_bounds__(256) void k_cvtT(const float* __restrict__ in, bf16* __restrict__ out, int R, int Cc){
  __shared__ float t[32][33];
  int bx = blockIdx.x * 32;
  int by = blockIdx.y * 32;
  int lx = threadIdx.x & 31, ly = threadIdx.x >> 5;
  #pragma unroll
  for (int s = 0; s < 4; s++){
    int k = by + ly + s*8;
    t[ly + s*8][lx] = in[(size_t)k * Cc + bx + lx];
  }
  __syncthreads();
  #pragma unroll
  for (int s = 0; s < 4; s++){
    int n = bx + ly + s*8;
    out[(size_t)n * R + by + lx] = f2b(t[lx][ly + s*8]);
  }
}

// ---------------- GEMM (m97 structure): C[M,N] = A[M,K] * B[K,N] + bias ----------------
// MODE 0: scatter into Q(*QSCALE)[B,NH,T,HD], K[B,NH,T,HD], Vt[B,NH,HD,T] (bf16)
// MODE 1: fp32 row-major output
template<int MODE>
__global__ __launch_bounds__(256) void k_gemm(
    const bf16* __restrict__ A, const bf16* __restrict__ BT,
    const float* __restrict__ bias,
    bf16* __restrict__ qo, bf16* __restrict__ ko, bf16* __restrict__ vo,
    float* __restrict__ fout,
    int M, int N, int K)
{
  __shared__ bf16 As[128][32];   // unpadded: required by global_load_lds contiguity
  __shared__ bf16 Bs[128][32];

  const int tid  = threadIdx.x;
  const int wave = tid >> 6, lane = tid & 63;
  const int wm = wave & 1, wn = wave >> 1;
  const int quad = lane >> 4, l15 = lane & 15;
  const int bm = blockIdx.x * 128;
  const int bn = blockIdx.y * 128;

  const int c0 = wave*64 + lane;
  const int c1 = c0 + 256;
  const bf16* gA0 = A  + (size_t)(bm + (c0>>2))*K + (c0&3)*8;
  const bf16* gA1 = A  + (size_t)(bm + (c1>>2))*K + (c1&3)*8;
  const bf16* gB0 = BT + (size_t)(bn + (c0>>2))*K + (c0&3)*8;
  const bf16* gB1 = BT + (size_t)(bn + (c1>>2))*K + (c1&3)*8;
  bf16* lA0 = &As[0][0] + wave*512;
  bf16* lA1 = &As[0][0] + 2048 + wave*512;
  bf16* lB0 = &Bs[0][0] + wave*512;
  bf16* lB1 = &Bs[0][0] + 2048 + wave*512;

  f32x4 acc[4][4] = {};

  for (int k0 = 0; k0 < K; k0 += 32){
    __syncthreads();
    async_load16(gA0, lA0); async_load16(gA1, lA1);
    async_load16(gB0, lB0); async_load16(gB1, lB1);
    gA0 += 32; gA1 += 32; gB0 += 32; gB1 += 32;
    __syncthreads();

    bf16x8 af[4], bfv[4];
    #pragma unroll
    for (int i = 0; i < 4; i++) af[i]  = *reinterpret_cast<const bf16x8*>(&As[wm*64 + i*16 + l15][quad*8]);
    #pragma unroll
    for (int j = 0; j < 4; j++) bfv[j] = *reinterpret_cast<const bf16x8*>(&Bs[wn*64 + j*16 + l15][quad*8]);
    #pragma unroll
    for (int i = 0; i < 4; i++)
      #pragma unroll
      for (int j = 0; j < 4; j++)
        acc[i][j] = __builtin_amdgcn_mfma_f32_16x16x32_bf16(af[i], bfv[j], acc[i][j], 0, 0, 0);
  }

  // epilogue: C/D layout row = quad*4 + reg, col = lane&15
  if (MODE == 0){
    // sec / head / batch are block- or wave-uniform (128 | 1024, 128 | 2048)
    const int sec = bn >> 10;
    const int bb2 = bm >> 11;
    const int tb  = (bm & (T_ - 1)) + wm*64 + quad*4;
    const int hn  = ((bn & 1023) >> 6) + wn;
    const size_t bhx = (size_t)(bb2 * NH_ + hn);
    if (sec == 2){
      #pragma unroll
      for (int j = 0; j < 4; j++){
        const int d = j*16 + l15;
        const float bj = bias[bn + wn*64 + j*16 + l15];
        bf16* vrow = vo + (bhx * HD_ + d) * (size_t)T_;
        #pragma unroll
        for (int i = 0; i < 4; i++){
          const int t = tb + i*16;
          bf16x4 pk;
          #pragma unroll
          for (int r = 0; r < 4; r++) pk[r] = f2bs(acc[i][j][r] + bj);
          *reinterpret_cast<bf16x4*>(vrow + t) = pk;
        }
      }
    } else {
      bf16* dst = (sec == 0) ? qo : ko;
      const float sc = (sec == 0) ? QSCALE : 1.0f;
      #pragma unroll
      for (int j = 0; j < 4; j++){
        const int d = j*16 + l15;
        const float bj = bias[bn + wn*64 + j*16 + l15];
        bf16* base = dst + bhx * T_ * HD_ + d;
        #pragma unroll
        for (int i = 0; i < 4; i++){
          bf16* p0 = base + (size_t)(tb + i*16) * HD_;
          #pragma unroll
          for (int r = 0; r < 4; r++)
            p0[(size_t)r * HD_] = f2b((acc[i][j][r] + bj) * sc);
        }
      }
    }
  } else {
    #pragma unroll
    for (int i = 0; i < 4; i++){
      #pragma unroll
      for (int j = 0; j < 4; j++){
        const int n = bn + wn*64 + j*16 + l15;
        const float bj = bias[n];
        float* p0 = fout + (size_t)(bm + wm*64 + i*16 + quad*4) * N + n;
        #pragma unroll
        for (int r = 0; r < 4; r++)
          p0[(size_t)r * N] = acc[i][j][r] + bj;
      }
    }
  }
}

// ---------------- flash attention (causal), transposed S^T/O^T, KV-tile=128 ----------------
// grid (64, 8): x = head (bh) so blocks sharing K/V land on one XCD; y = pair index.
// Block pair {b, 15-b}: 17 KV-iterations of 128 each (balanced).
// Softmax in exp2 domain (Q pre-scaled by 0.125*log2e). Denominator accumulated by MFMA
// via a ones-row appended to V^T (d=64), rescaled by alpha for free.
__global__ __launch_bounds__(256) void k_attn(
    const bf16* __restrict__ Q, const bf16* __restrict__ Kg,
    const bf16* __restrict__ Vt, bf16* __restrict__ Y)
{
  __shared__ bf16 Qs[128][72];   // [q][d]
  __shared__ bf16 Ks[128][72];   // [kv][d]
  __shared__ bf16 Vs[80][136];   // [d][kv]; rows 64..79: row 64 = ones, rest zero

  const int bh = blockIdx.x;
  const int bb = bh >> 4, hh = bh & 15;
  const int tid  = threadIdx.x;
  const int wave = tid >> 6, lane = tid & 63;
  const int quad = lane >> 4, l15 = lane & 15;

  const size_t baseQK = (size_t)bh * T_ * HD_;
  const size_t baseV  = (size_t)bh * HD_ * T_;

  // staging geometry (per-thread, loop-invariant)
  const bf16* kp[4]; const bf16* vp[4];
  bf16* kl[4]; bf16* vl[4];
  #pragma unroll
  for (int s = 0; s < 4; s++){
    int c = tid + s*256;
    int krow = c >> 3, kcol = (c & 7) * 8;      // K tile: 128 rows x 64 d
    kp[s] = Kg + baseQK + (size_t)krow * HD_ + kcol;
    kl[s] = &Ks[krow][kcol];
    int vrow = c >> 4, vcol = (c & 15) * 8;     // V^T tile: 64 d x 128 kv
    vp[s] = Vt + baseV + (size_t)vrow * T_ + vcol;
    vl[s] = &Vs[vrow][vcol];
  }

  // ones/zeros pad rows of Vs (once; staging never touches rows >= 64)
  {
    int row = 64 + (tid >> 4), col = (tid & 15) * 8;
    short v = f2bs(row == 64 ? 1.0f : 0.0f);
    bf16x8 fill = { v, v, v, v, v, v, v, v };
    *reinterpret_cast<bf16x8*>(&Vs[row][col]) = fill;
  }

  for (int phase = 0; phase < 2; phase++){
    const int qt = phase ? (15 - blockIdx.y) : blockIdx.y;

    // stage Q tile [128][64] (pre-scaled by QSCALE upstream); prev-phase reads already
    // drained by last iteration's trailing barrier.
    #pragma unroll
    for (int s = 0; s < 4; s++){
      int c = tid + s*256;
      int row = c >> 3, col = (c & 7) * 8;
      *(float4*)(&Qs[row][col]) = *(const float4*)(Q + baseQK + (size_t)(qt*128 + row)*HD_ + col);
    }

    float m_i[2] = {-1e30f, -1e30f};
    f32x4 o[2][5] = {};            // td=4 row0 = softmax denominator

    // prefetch j=0
    float4 kr[4], vr[4];
    #pragma unroll
    for (int s = 0; s < 4; s++){
      kr[s] = *(const float4*)(kp[s]);
      vr[s] = *(const float4*)(vp[s]);
    }

    for (int j = 0; j <= qt; j++){
      #pragma unroll
      for (int s = 0; s < 4; s++){
        *(float4*)kl[s] = kr[s];
        *(float4*)vl[s] = vr[s];
      }
      __syncthreads();
      if (j < qt){
        #pragma unroll
        for (int s = 0; s < 4; s++){
          kr[s] = *(const float4*)(kp[s] + (size_t)(j+1) * 128 * HD_);
          vr[s] = *(const float4*)(vp[s] + (j+1) * 128);
        }
      }

      // S^T = K * Q^T : per wave q in [wave*32, wave*32+32), kv 0..127
      f32x4 st[2][8] = {};
      #pragma unroll
      for (int ks = 0; ks < 2; ks++){
        bf16x8 qf[2];
        #pragma unroll
        for (int tq = 0; tq < 2; tq++)
          qf[tq] = *reinterpret_cast<const bf16x8*>(&Qs[wave*32 + tq*16 + l15][ks*32 + quad*8]);
        #pragma unroll
        for (int tk = 0; tk < 8; tk++){
          bf16x8 kf = *reinterpret_cast<const bf16x8*>(&Ks[tk*16 + l15][ks*32 + quad*8]);
          st[0][tk] = __builtin_amdgcn_mfma_f32_16x16x32_bf16(kf, qf[0], st[0][tk], 0, 0, 0);
          st[1][tk] = __builtin_amdgcn_mfma_f32_16x16x32_bf16(kf, qf[1], st[1][tk], 0, 0, 0);
        }
      }

      const bool diag = (j == qt);
      bf16x4 pf[2][8];
      #pragma unroll
      for (int tq = 0; tq < 2; tq++){
        const int ql = wave*32 + tq*16 + l15;     // local q (j==qt => same tile)
        if (diag){
          #pragma unroll
          for (int tk = 0; tk < 8; tk++){
            const int kvb = tk*16 + quad*4;
            #pragma unroll
            for (int r = 0; r < 4; r++)
              if (kvb + r > ql) st[tq][tk][r] = -1e30f;
          }
        }
        float mx = -1e30f;
        #pragma unroll
        for (int tk = 0; tk < 8; tk++)
          #pragma unroll
          for (int r = 0; r < 4; r++) mx = fmaxf(mx, st[tq][tk][r]);
        mx = fmaxf(mx, __shfl_xor(mx, 16, 64));
        mx = fmaxf(mx, __shfl_xor(mx, 32, 64));
        const float mn = fmaxf(m_i[tq], mx);
        const float alpha = exp2f(m_i[tq] - mn);
        m_i[tq] = mn;
        #pragma unroll
        for (int tk = 0; tk < 8; tk++){
          bf16x4 pk;
          #pragma unroll
          for (int r = 0; r < 4; r++) pk[r] = f2bs(exp2f(st[tq][tk][r] - mn));
          pf[tq][tk] = pk;
        }
        #pragma unroll
        for (int td = 0; td < 5; td++)
          #pragma unroll
          for (int r = 0; r < 4; r++) o[tq][td][r] *= alpha;
      }

      // O^T += V^T * P^T  (td=4 accumulates the denominator via the ones-row)
      #pragma unroll
      for (int td = 0; td < 5; td++){
        #pragma unroll
        for (int tk = 0; tk < 8; tk++){
          bf16x4 vf = *reinterpret_cast<const bf16x4*>(&Vs[td*16 + l15][tk*16 + quad*4]);
          o[0][td] = __builtin_amdgcn_mfma_f32_16x16x16bf16_1k(vf, pf[0][tk], o[0][td], 0, 0, 0);
          o[1][td] = __builtin_amdgcn_mfma_f32_16x16x16bf16_1k(vf, pf[1][tk], o[1][td], 0, 0, 0);
        }
      }
      __syncthreads();   // LDS consumed; next iter / next phase may overwrite
    }

    // normalize + write Y[B*T][C]
    #pragma unroll
    for (int tq = 0; tq < 2; tq++){
      const float l = __shfl(o[tq][4][0], l15, 64);   // lanes 0..15 (quad 0) hold d=64 row
      const float inv = 1.0f / l;
      const int t = qt*128 + wave*32 + tq*16 + l15;
      bf16* yrow = Y + ((size_t)(bb * T_ + t)) * C_ + hh * HD_;
      #pragma unroll
      for (int td = 0; td < 4; td++){
        bf16x4 pk;
        #pragma unroll
        for (int r = 0; r < 4; r++) pk[r] = f2bs(o[tq][td][r] * inv);
        *reinterpret_cast<bf16x4*>(yrow + td*16 + quad*4) = pk;
      }
    }
  }
}

// ---------------- launcher ----------------

extern "C" void kernel_launch(void* const* d_in, const int* in_sizes, int n_in,
                              void* d_out, int out_size, void* d_ws, size_t ws_size,
                              hipStream_t stream) {
  const float* x     = (const float*)d_in[0];
  const float* Wqkv  = (const float*)d_in[1];
  const float* bqkv  = (const float*)d_in[2];
  const float* Wproj = (const float*)d_in[3];
  const float* bproj = (const float*)d_in[4];
  float* out = (float*)d_out;

  const size_t M = (size_t)B_ * T_;
  char* w = (char*)d_ws;
  bf16* xb     = (bf16*)w;  w += M * C_ * 2;
  bf16* WqkvT  = (bf16*)w;  w += (size_t)3 * C_ * C_ * 2;
  bf16* WprojT = (bf16*)w;  w += (size_t)C_ * C_ * 2;
  bf16* Qb     = (bf16*)w;  w += M * C_ * 2;
  bf16* Kb     = (bf16*)w;  w += M * C_ * 2;
  bf16* Vtb    = (bf16*)w;  w += M * C_ * 2;
  bf16* Yb     = (bf16*)w;  w += M * C_ * 2;

  {
    int n = (int)(M * C_);
    k_cvt4<<<dim3((n/4 + 255)/256), dim3(256), 0, stream>>>(x, xb, n);
  }
  k_cvtT<<<dim3((3*C_)/32, C_/32), dim3(256), 0, stream>>>(Wqkv, WqkvT, C_, 3*C_);
  k_cvtT<<<dim3(C_/32, C_/32), dim3(256), 0, stream>>>(Wproj, WprojT, C_, C_);
  k_gemm<0><<<dim3(M/128, (3*C_)/128), dim3(256), 0, stream>>>(
      xb, WqkvT, bqkv, Qb, Kb, Vtb, nullptr, (int)M, 3*C_, C_);
  k_attn<<<dim3(64, 8), dim3(256), 0, stream>>>(Qb, Kb, Vtb, Yb);
  k_gemm<1><<<dim3(M/128, C_/128), dim3(256), 0, stream>>>(
      Yb, WprojT, bproj, nullptr, nullptr, nullptr, out, (int)M, C_, C_);
}

// Round 4
// 295.533 us; speedup vs baseline: 1.2270x; 1.2270x over previous
//
#include <hip/hip_runtime.h>
#include <hip/hip_bf16.h>
#include <math.h>

#define B_  4
#define T_  2048
#define C_  1024
#define NH_ 16
#define HD_ 64

using bf16 = __hip_bfloat16;
typedef __attribute__((ext_vector_type(8))) short bf16x8;   // 8 bf16 (4 VGPRs)
typedef __attribute__((ext_vector_type(4))) short bf16x4;   // 4 bf16 (2 VGPRs)
typedef __attribute__((ext_vector_type(4))) float f32x4;

__device__ __forceinline__ bf16 f2b(float f){ return __float2bfloat16(f); }
__device__ __forceinline__ short f2bs(float f){ bf16 b = __float2bfloat16(f); return *(short*)&b; }

__device__ __forceinline__ void async_load16(const bf16* g, bf16* l){
  __builtin_amdgcn_global_load_lds((const __attribute__((address_space(1))) unsigned int*)g,
                                   (__attribute__((address_space(3))) unsigned int*)l,
                                   16, 0, 0);
}

// 0.125 (1/sqrt(64)) * log2(e): softmax runs in exp2 domain
#define QSCALE 0.18033688011112042f

// ---------------- conversion kernels ----------------

__global__ __launch_bounds__(256) void k_cvt4(const float* __restrict__ in, bf16* __restrict__ out, int n){
  int i = (blockIdx.x * 256 + threadIdx.x) * 4;
  if (i < n){
    float4 f = *(const float4*)(in + i);
    ushort4 u;
    u.x = (unsigned short)f2bs(f.x);
    u.y = (unsigned short)f2bs(f.y);
    u.z = (unsigned short)f2bs(f.z);
    u.w = (unsigned short)f2bs(f.w);
    *(ushort4*)(out + i) = u;
  }
}

// in [R][Cc] fp32 -> out [Cc][R] bf16, LDS tile transpose
__global__ __launch_bounds__(256) void k_cvtT(const float* __restrict__ in, bf16* __restrict__ out, int R, int Cc){
  __shared__ float t[32][33];
  int bx = blockIdx.x * 32;
  int by = blockIdx.y * 32;
  int lx = threadIdx.x & 31, ly = threadIdx.x >> 5;
  #pragma unroll
  for (int s = 0; s < 4; s++){
    int k = by + ly + s*8;
    t[ly + s*8][lx] = in[(size_t)k * Cc + bx + lx];
  }
  __syncthreads();
  #pragma unroll
  for (int s = 0; s < 4; s++){
    int n = bx + ly + s*8;
    out[(size_t)n * R + by + lx] = f2b(t[lx][ly + s*8]);
  }
}

// ---------------- GEMM (m97 structure): C[M,N] = A[M,K] * B[K,N] + bias ----------------
// MODE 0: scatter into Q(*QSCALE)[B,NH,T,HD], K[B,NH,T,HD], Vt[B,NH,HD,T] (bf16)
// MODE 1: fp32 row-major output
template<int MODE>
__global__ __launch_bounds__(256) void k_gemm(
    const bf16* __restrict__ A, const bf16* __restrict__ BT,
    const float* __restrict__ bias,
    bf16* __restrict__ qo, bf16* __restrict__ ko, bf16* __restrict__ vo,
    float* __restrict__ fout,
    int M, int N, int K)
{
  __shared__ bf16 As[128][32];   // unpadded: required by global_load_lds contiguity
  __shared__ bf16 Bs[128][32];

  const int tid  = threadIdx.x;
  const int wave = tid >> 6, lane = tid & 63;
  const int wm = wave & 1, wn = wave >> 1;
  const int quad = lane >> 4, l15 = lane & 15;
  const int bm = blockIdx.x * 128;
  const int bn = blockIdx.y * 128;

  const int c0 = wave*64 + lane;
  const int c1 = c0 + 256;
  const bf16* gA0 = A  + (size_t)(bm + (c0>>2))*K + (c0&3)*8;
  const bf16* gA1 = A  + (size_t)(bm + (c1>>2))*K + (c1&3)*8;
  const bf16* gB0 = BT + (size_t)(bn + (c0>>2))*K + (c0&3)*8;
  const bf16* gB1 = BT + (size_t)(bn + (c1>>2))*K + (c1&3)*8;
  bf16* lA0 = &As[0][0] + wave*512;
  bf16* lA1 = &As[0][0] + 2048 + wave*512;
  bf16* lB0 = &Bs[0][0] + wave*512;
  bf16* lB1 = &Bs[0][0] + 2048 + wave*512;

  f32x4 acc[4][4] = {};

  for (int k0 = 0; k0 < K; k0 += 32){
    __syncthreads();
    async_load16(gA0, lA0); async_load16(gA1, lA1);
    async_load16(gB0, lB0); async_load16(gB1, lB1);
    gA0 += 32; gA1 += 32; gB0 += 32; gB1 += 32;
    __syncthreads();

    bf16x8 af[4], bfv[4];
    #pragma unroll
    for (int i = 0; i < 4; i++) af[i]  = *reinterpret_cast<const bf16x8*>(&As[wm*64 + i*16 + l15][quad*8]);
    #pragma unroll
    for (int j = 0; j < 4; j++) bfv[j] = *reinterpret_cast<const bf16x8*>(&Bs[wn*64 + j*16 + l15][quad*8]);
    #pragma unroll
    for (int i = 0; i < 4; i++)
      #pragma unroll
      for (int j = 0; j < 4; j++)
        acc[i][j] = __builtin_amdgcn_mfma_f32_16x16x32_bf16(af[i], bfv[j], acc[i][j], 0, 0, 0);
  }

  // epilogue: C/D layout row = quad*4 + reg, col = lane&15
  if (MODE == 0){
    const int sec = bn >> 10;
    const int bb2 = bm >> 11;
    const int tb  = (bm & (T_ - 1)) + wm*64 + quad*4;
    const int hn  = ((bn & 1023) >> 6) + wn;
    const size_t bhx = (size_t)(bb2 * NH_ + hn);
    if (sec == 2){
      #pragma unroll
      for (int j = 0; j < 4; j++){
        const int d = j*16 + l15;
        const float bj = bias[bn + wn*64 + j*16 + l15];
        bf16* vrow = vo + (bhx * HD_ + d) * (size_t)T_;
        #pragma unroll
        for (int i = 0; i < 4; i++){
          const int t = tb + i*16;
          bf16x4 pk;
          #pragma unroll
          for (int r = 0; r < 4; r++) pk[r] = f2bs(acc[i][j][r] + bj);
          *reinterpret_cast<bf16x4*>(vrow + t) = pk;
        }
      }
    } else {
      bf16* dst = (sec == 0) ? qo : ko;
      const float sc = (sec == 0) ? QSCALE : 1.0f;
      #pragma unroll
      for (int j = 0; j < 4; j++){
        const int d = j*16 + l15;
        const float bj = bias[bn + wn*64 + j*16 + l15];
        bf16* base = dst + bhx * T_ * HD_ + d;
        #pragma unroll
        for (int i = 0; i < 4; i++){
          bf16* p0 = base + (size_t)(tb + i*16) * HD_;
          #pragma unroll
          for (int r = 0; r < 4; r++)
            p0[(size_t)r * HD_] = f2b((acc[i][j][r] + bj) * sc);
        }
      }
    }
  } else {
    #pragma unroll
    for (int i = 0; i < 4; i++){
      #pragma unroll
      for (int j = 0; j < 4; j++){
        const int n = bn + wn*64 + j*16 + l15;
        const float bj = bias[n];
        float* p0 = fout + (size_t)(bm + wm*64 + i*16 + quad*4) * N + n;
        #pragma unroll
        for (int r = 0; r < 4; r++)
          p0[(size_t)r * N] = acc[i][j][r] + bj;
      }
    }
  }
}

// ---------------- flash attention (causal), transposed S^T/O^T, KV-tile=64 ----------------
// grid (64, 8): x = head (bh) -> all blocks sharing a head's K/V land on XCD bh%8
//   (8 heads/XCD x 512 KB K/V = L2-resident; round-3 measured FETCH 147->37 MB).
// Block pair {b, 15-b}: 34 KV-iterations total (balanced).
// Softmax in exp2 domain (Q pre-scaled by 0.125*log2e upstream).
// Softmax denominator accumulated on the MFMA pipe via a ones-row at d=64 of V^T
// (alpha-rescaled for free with O); VALU row-sum + 2 shuffles per iter removed.
// KV=64 keeps LDS at ~39 KB -> 4 blocks/CU (round-3's KV=128 at 75 KB halved occupancy).
__global__ __launch_bounds__(256) void k_attn(
    const bf16* __restrict__ Q, const bf16* __restrict__ Kg,
    const bf16* __restrict__ Vt, bf16* __restrict__ Y)
{
  __shared__ bf16 Qs[128][72];   // [q][d]
  __shared__ bf16 Ks[64][72];    // [kv][d]
  __shared__ bf16 Vs[80][72];    // [d][kv]; rows 64..79: row 64 = ones, rest zero

  const int bh = blockIdx.x;
  const int bb = bh >> 4, hh = bh & 15;
  const int tid  = threadIdx.x;
  const int wave = tid >> 6, lane = tid & 63;
  const int quad = lane >> 4, l15 = lane & 15;

  const size_t baseQK = (size_t)bh * T_ * HD_;
  const size_t baseV  = (size_t)bh * HD_ * T_;

  // ones/zeros pad rows of Vs (written once; staging never touches rows >= 64)
  if (tid < 128){
    int row = 64 + (tid >> 3), col = (tid & 7) * 8;
    short v = f2bs(row == 64 ? 1.0f : 0.0f);
    bf16x8 fill = { v, v, v, v, v, v, v, v };
    *reinterpret_cast<bf16x8*>(&Vs[row][col]) = fill;
  }

  for (int phase = 0; phase < 2; phase++){
    const int qt = phase ? (15 - blockIdx.y) : blockIdx.y;

    // stage Q tile [128][64]; prev phase's Qs reads drained by last iter's trailing barrier
    #pragma unroll
    for (int s = 0; s < 4; s++){
      int c = tid + s*256;
      int row = c >> 3, col = (c & 7) * 8;
      *(float4*)(&Qs[row][col]) = *(const float4*)(Q + baseQK + (size_t)(qt*128 + row)*HD_ + col);
    }

    float m_i[2] = {-1e30f, -1e30f};
    f32x4 o[2][5] = {};            // td=4 row0 (d=64) = softmax denominator

    const int jmax = 2*qt + 1;
    for (int j = 0; j <= jmax; j++){
      // stage K [64][64] and V^T slab [64 d][64 kv]
      #pragma unroll
      for (int s = 0; s < 2; s++){
        int c = tid + s*256;
        int row = c >> 3, col = (c & 7) * 8;
        *(float4*)(&Ks[row][col]) = *(const float4*)(Kg + baseQK + (size_t)(j*64 + row)*HD_ + col);
        *(float4*)(&Vs[row][col]) = *(const float4*)(Vt + baseV  + (size_t)row*T_ + j*64 + col);
      }
      __syncthreads();   // staging (and Qs/ones at j=0) visible

      // S^T = K * Q^T : wave covers q in [wave*32, wave*32+32), kv 0..63
      f32x4 st[2][4] = {};
      #pragma unroll
      for (int ks = 0; ks < 2; ks++){
        bf16x8 qf[2], kf[4];
        #pragma unroll
        for (int tq = 0; tq < 2; tq++)
          qf[tq] = *reinterpret_cast<const bf16x8*>(&Qs[wave*32 + tq*16 + l15][ks*32 + quad*8]);
        #pragma unroll
        for (int tk = 0; tk < 4; tk++)
          kf[tk] = *reinterpret_cast<const bf16x8*>(&Ks[tk*16 + l15][ks*32 + quad*8]);
        #pragma unroll
        for (int tq = 0; tq < 2; tq++)
          #pragma unroll
          for (int tk = 0; tk < 4; tk++)
            st[tq][tk] = __builtin_amdgcn_mfma_f32_16x16x32_bf16(kf[tk], qf[tq], st[tq][tk], 0, 0, 0);
      }

      const bool diag = (j >= 2*qt);
      bf16x4 pf[2][4];
      #pragma unroll
      for (int tq = 0; tq < 2; tq++){
        const int qg = qt*128 + wave*32 + tq*16 + l15;
        if (diag){
          #pragma unroll
          for (int tk = 0; tk < 4; tk++){
            const int kvb = j*64 + tk*16 + quad*4;
            #pragma unroll
            for (int r = 0; r < 4; r++)
              if (kvb + r > qg) st[tq][tk][r] = -1e30f;
          }
        }
        float mx = -1e30f;
        #pragma unroll
        for (int tk = 0; tk < 4; tk++)
          #pragma unroll
          for (int r = 0; r < 4; r++) mx = fmaxf(mx, st[tq][tk][r]);
        mx = fmaxf(mx, __shfl_xor(mx, 16, 64));
        mx = fmaxf(mx, __shfl_xor(mx, 32, 64));
        const float mn = fmaxf(m_i[tq], mx);
        const float alpha = exp2f(m_i[tq] - mn);
        m_i[tq] = mn;
        #pragma unroll
        for (int tk = 0; tk < 4; tk++){
          bf16x4 pk;
          #pragma unroll
          for (int r = 0; r < 4; r++) pk[r] = f2bs(exp2f(st[tq][tk][r] - mn));
          pf[tq][tk] = pk;
        }
        #pragma unroll
        for (int td = 0; td < 5; td++)
          #pragma unroll
          for (int r = 0; r < 4; r++) o[tq][td][r] *= alpha;
      }

      // O^T += V^T * P^T  (td=4 accumulates the denominator via the ones-row)
      #pragma unroll
      for (int td = 0; td < 5; td++){
        #pragma unroll
        for (int tk = 0; tk < 4; tk++){
          bf16x4 vf = *reinterpret_cast<const bf16x4*>(&Vs[td*16 + l15][tk*16 + quad*4]);
          o[0][td] = __builtin_amdgcn_mfma_f32_16x16x16bf16_1k(vf, pf[0][tk], o[0][td], 0, 0, 0);
          o[1][td] = __builtin_amdgcn_mfma_f32_16x16x16bf16_1k(vf, pf[1][tk], o[1][td], 0, 0, 0);
        }
      }
      __syncthreads();   // LDS consumed; next iter / next phase may overwrite
    }

    // normalize + write Y[B*T][C]
    #pragma unroll
    for (int tq = 0; tq < 2; tq++){
      const float l = __shfl(o[tq][4][0], l15, 64);   // quad-0 lanes hold d=64 row
      const float inv = 1.0f / l;
      const int t = qt*128 + wave*32 + tq*16 + l15;
      bf16* yrow = Y + ((size_t)(bb * T_ + t)) * C_ + hh * HD_;
      #pragma unroll
      for (int td = 0; td < 4; td++){
        bf16x4 pk;
        #pragma unroll
        for (int r = 0; r < 4; r++) pk[r] = f2bs(o[tq][td][r] * inv);
        *reinterpret_cast<bf16x4*>(yrow + td*16 + quad*4) = pk;
      }
    }
  }
}

// ---------------- launcher ----------------

extern "C" void kernel_launch(void* const* d_in, const int* in_sizes, int n_in,
                              void* d_out, int out_size, void* d_ws, size_t ws_size,
                              hipStream_t stream) {
  const float* x     = (const float*)d_in[0];
  const float* Wqkv  = (const float*)d_in[1];
  const float* bqkv  = (const float*)d_in[2];
  const float* Wproj = (const float*)d_in[3];
  const float* bproj = (const float*)d_in[4];
  float* out = (float*)d_out;

  const size_t M = (size_t)B_ * T_;
  char* w = (char*)d_ws;
  bf16* xb     = (bf16*)w;  w += M * C_ * 2;
  bf16* WqkvT  = (bf16*)w;  w += (size_t)3 * C_ * C_ * 2;
  bf16* WprojT = (bf16*)w;  w += (size_t)C_ * C_ * 2;
  bf16* Qb     = (bf16*)w;  w += M * C_ * 2;
  bf16* Kb     = (bf16*)w;  w += M * C_ * 2;
  bf16* Vtb    = (bf16*)w;  w += M * C_ * 2;
  bf16* Yb     = (bf16*)w;  w += M * C_ * 2;

  {
    int n = (int)(M * C_);
    k_cvt4<<<dim3((n/4 + 255)/256), dim3(256), 0, stream>>>(x, xb, n);
  }
  k_cvtT<<<dim3((3*C_)/32, C_/32), dim3(256), 0, stream>>>(Wqkv, WqkvT, C_, 3*C_);
  k_cvtT<<<dim3(C_/32, C_/32), dim3(256), 0, stream>>>(Wproj, WprojT, C_, C_);
  k_gemm<0><<<dim3(M/128, (3*C_)/128), dim3(256), 0, stream>>>(
      xb, WqkvT, bqkv, Qb, Kb, Vtb, nullptr, (int)M, 3*C_, C_);
  k_attn<<<dim3(64, 8), dim3(256), 0, stream>>>(Qb, Kb, Vtb, Yb);
  k_gemm<1><<<dim3(M/128, C_/128), dim3(256), 0, stream>>>(
      Yb, WprojT, bproj, nullptr, nullptr, nullptr, out, (int)M, C_, C_);
}